// Round 1
// baseline (6260.825 us; speedup 1.0000x reference)
//
#include <hip/hip_runtime.h>

// DETM forward. Round 1: correctness-first fp32 pipeline.
//   - beta logits stored as bf16 in d_ws (needs ~108 MB workspace)
//   - LSTM scans: single-workgroup sequential kernels, f16 weights + v_dot2_f32_f16
//   - all big GEMMs: fp32 128x128 tile, 8x8 microtile, K-split w/ atomics for long-K
// Output: 5 floats = loss, nll, kl_eta, kl_theta, kl_alpha.

typedef unsigned int u32;
typedef unsigned short u16;
typedef _Float16 f16;
typedef f16 f16x2 __attribute__((ext_vector_type(2)));

#define LOG_DELTA (-5.2983174f)
#define COEFF 781.25f   // TRAIN_SIZE / B = 100000/128

__device__ __forceinline__ float bf2f(u16 a) { return __uint_as_float(((u32)a) << 16); }
__device__ __forceinline__ u16 f2bf(float f) {
  u32 u = __float_as_uint(f);
  u32 r = (u + 0x7fffu + ((u >> 16) & 1u)) >> 16;
  return (u16)r;
}
__device__ __forceinline__ float fdot2(u32 w, u32 h, float acc) {
  return __builtin_amdgcn_fdot2(__builtin_bit_cast(f16x2, w), __builtin_bit_cast(f16x2, h), acc, false);
}
__device__ __forceinline__ float sigm(float x) { return 1.f / (1.f + __expf(-x)); }

// ---------------- small utility kernels ----------------

__global__ __launch_bounds__(64) void k_zero(float* __restrict__ accum) {
  if (threadIdx.x < 8) accum[threadIdx.x] = 0.f;
}

__global__ __launch_bounds__(256) void k_nb(const float* __restrict__ bows, float* __restrict__ nb) {
  __shared__ float red[256];
  const int b = blockIdx.x, tid = threadIdx.x;
  float s = 0.f;
  for (int v = tid; v < 10000; v += 256) s += bows[b * 10000 + v];
  red[tid] = s; __syncthreads();
  for (int o = 128; o > 0; o >>= 1) { if (tid < o) red[tid] += red[tid + o]; __syncthreads(); }
  const float inv = 1.f / red[0];
  for (int v = tid; v < 10000; v += 256) nb[b * 10000 + v] = bows[b * 10000 + v] * inv;
}

__global__ __launch_bounds__(256) void k_cvt_f16(const float* __restrict__ w, u16* __restrict__ out, int n) {
  int i = blockIdx.x * 256 + threadIdx.x;
  if (i < n) { f16 h = (f16)w[i]; out[i] = __builtin_bit_cast(u16, h); }
}

__global__ __launch_bounds__(256) void k_bsum(const float* __restrict__ a, const float* __restrict__ b,
                                              float* __restrict__ o, int n) {
  int i = blockIdx.x * 256 + threadIdx.x;
  if (i < n) o[i] = a[i] + b[i];
}

__global__ __launch_bounds__(256) void k_fill(float* __restrict__ C, const float* __restrict__ bias,
                                              int N, int total) {
  for (int i = blockIdx.x * 256 + threadIdx.x; i < total; i += gridDim.x * 256)
    C[i] = bias[i % N];
}

__global__ __launch_bounds__(256) void k_relu(float* __restrict__ C, int total) {
  for (int i = blockIdx.x * 256 + threadIdx.x; i < total; i += gridDim.x * 256) {
    float v = C[i];
    C[i] = v > 0.f ? v : 0.f;
  }
}

// ---------------- generic fp32 GEMM: C[M,N] = A[M,K] @ B[N,K]^T ----------------
// AMODE: 0 plain A; 1 alphas (A = mu_q_alpha [K=50][T=100][R=300], row m -> t=m/50,k=m%50)
//        2 concat (A = nb [128][10000], cols >=10000 come from etas[times[m]])
// EPI:   0 store; 1 +bias store; 2 +bias relu store; 3 store bf16 (no bias); 5 atomicAdd (K-split)

#define GT 128
#define GBK 16

template<int AMODE, int EPI>
__global__ __launch_bounds__(256) void gemm_abT(
    const float* __restrict__ A, const float* __restrict__ Bm,
    const float* __restrict__ bias, float* __restrict__ C, u16* __restrict__ Cb,
    int M, int N, int Kd, int lda, int ldb,
    const int* __restrict__ times, const float* __restrict__ etas)
{
  __shared__ __align__(16) float As[GBK][GT + 4];
  __shared__ __align__(16) float Bs[GBK][GT + 4];
  const int tid = threadIdx.x;
  const int tx = tid & 15, ty = tid >> 4;
  const int m_base = blockIdx.x * GT, n_base = blockIdx.y * GT;
  float acc[8][8] = {};
  const int nkt = (Kd + GBK - 1) / GBK;
  const int per = (nkt + gridDim.z - 1) / gridDim.z;
  const int kt0 = blockIdx.z * per;
  const int kt1 = min(nkt, kt0 + per);
  const int lkk = tid & 15;
  const int lmm = tid >> 4;
  for (int kt = kt0; kt < kt1; ++kt) {
    const int kg = kt * GBK + lkk;
#pragma unroll
    for (int i = 0; i < 8; ++i) {
      int m = m_base + lmm + i * 16;
      float v = 0.f;
      if (m < M && kg < Kd) {
        if (AMODE == 0) v = A[(size_t)m * lda + kg];
        else if (AMODE == 1) { int tt = m / 50; int k2 = m - tt * 50; v = A[k2 * 30000 + tt * 300 + kg]; }
        else {
          if (kg < 10000) v = A[(size_t)m * 10000 + kg];
          else v = etas[times[m] * 50 + (kg - 10000)];
        }
      }
      As[lkk][lmm + i * 16] = v;
    }
#pragma unroll
    for (int i = 0; i < 8; ++i) {
      int n = n_base + lmm + i * 16;
      float v = 0.f;
      if (n < N && kg < Kd) v = Bm[(size_t)n * ldb + kg];
      Bs[lkk][lmm + i * 16] = v;
    }
    __syncthreads();
#pragma unroll
    for (int kk = 0; kk < GBK; ++kk) {
      const float4* ap = (const float4*)&As[kk][ty * 8];
      const float4* bp = (const float4*)&Bs[kk][tx * 8];
      float4 a0 = ap[0], a1 = ap[1];
      float4 b0 = bp[0], b1 = bp[1];
      float av[8] = {a0.x, a0.y, a0.z, a0.w, a1.x, a1.y, a1.z, a1.w};
      float bv[8] = {b0.x, b0.y, b0.z, b0.w, b1.x, b1.y, b1.z, b1.w};
#pragma unroll
      for (int i = 0; i < 8; ++i)
#pragma unroll
        for (int j = 0; j < 8; ++j) acc[i][j] += av[i] * bv[j];
    }
    __syncthreads();
  }
#pragma unroll
  for (int i = 0; i < 8; ++i) {
    int m = m_base + ty * 8 + i;
    if (m >= M) continue;
#pragma unroll
    for (int j = 0; j < 8; ++j) {
      int n = n_base + tx * 8 + j;
      if (n >= N) continue;
      float v = acc[i][j];
      if (EPI == 1) { C[(size_t)m * N + n] = v + bias[n]; }
      else if (EPI == 2) { v += bias[n]; C[(size_t)m * N + n] = v > 0.f ? v : 0.f; }
      else if (EPI == 3) { Cb[(size_t)m * N + n] = f2bf(v); }
      else if (EPI == 5) { atomicAdd(&C[(size_t)m * N + n], v); }
      else { C[(size_t)m * N + n] = v; }
    }
  }
}

// ---------------- sequential LSTM layer scan (single workgroup, 512 threads) ----------------
// gates r = Xproj[t,r] + Whh[r,:] @ h  (Whh in f16, v_dot2_f32_f16, fp32 accum)
// thread layout (phase A): tid<400: j = tid%200 (hidden unit), s = tid/200 (k-split half),
// each thread computes its half-dot for all 4 gate rows j,200+j,400+j,600+j.
// do_eta: layer 2 also runs the eta scan step (mu/ls matvec [50,250], KL accumulation).

__global__ __launch_bounds__(512) void lstm_scan(
    const u16* __restrict__ whh_h,   // 800*200 f16 (this layer)
    const float* __restrict__ xproj, // [100][800]
    float* __restrict__ hseq,        // [100][200] output (unused if do_eta)
    const float* __restrict__ muW, const float* __restrict__ mub,
    const float* __restrict__ lsW, const float* __restrict__ lsb,
    float* __restrict__ etas, float* __restrict__ accum, const int do_eta)
{
  __shared__ __align__(16) float xcat[252];  // [0..199]=h, [200..249]=eta_prev, [250..251]=0 pad
  __shared__ __align__(16) u16 h2s[200];     // h in f16 for dot2
  __shared__ float pg[800];
  __shared__ float pc[400];
  __shared__ float mu_ls[100];
  const int tid = threadIdx.x;
  if (tid < 252) xcat[tid] = 0.f;
  if (tid < 200) h2s[tid] = 0;
  float c_reg = 0.f, klacc = 0.f;
  float a0 = 0.f, a1 = 0.f, a2 = 0.f, a3 = 0.f;
  const int s = tid / 200;
  const int j = tid - s * 200;
  __syncthreads();
  for (int t = 0; t < 100; ++t) {
    if (tid < 400) {
      if (s == 0) {
        a0 = xproj[t * 800 + j];
        a1 = xproj[t * 800 + 200 + j];
        a2 = xproj[t * 800 + 400 + j];
        a3 = xproj[t * 800 + 600 + j];
      } else { a0 = a1 = a2 = a3 = 0.f; }
      const int c0 = s ? 12 : 0, c1 = s ? 25 : 12;
      const uint4* H4 = (const uint4*)h2s;
      const uint4* W4 = (const uint4*)whh_h;   // row = 25 uint4 (200 f16)
      for (int c = c0; c < c1; ++c) {
        uint4 hv = H4[c];
        uint4 w0 = W4[j * 25 + c];
        uint4 w1 = W4[(200 + j) * 25 + c];
        uint4 w2 = W4[(400 + j) * 25 + c];
        uint4 w3 = W4[(600 + j) * 25 + c];
        a0 = fdot2(w0.x, hv.x, a0); a0 = fdot2(w0.y, hv.y, a0); a0 = fdot2(w0.z, hv.z, a0); a0 = fdot2(w0.w, hv.w, a0);
        a1 = fdot2(w1.x, hv.x, a1); a1 = fdot2(w1.y, hv.y, a1); a1 = fdot2(w1.z, hv.z, a1); a1 = fdot2(w1.w, hv.w, a1);
        a2 = fdot2(w2.x, hv.x, a2); a2 = fdot2(w2.y, hv.y, a2); a2 = fdot2(w2.z, hv.z, a2); a2 = fdot2(w2.w, hv.w, a2);
        a3 = fdot2(w3.x, hv.x, a3); a3 = fdot2(w3.y, hv.y, a3); a3 = fdot2(w3.z, hv.z, a3); a3 = fdot2(w3.w, hv.w, a3);
      }
      if (s == 1) { pg[j] = a0; pg[200 + j] = a1; pg[400 + j] = a2; pg[600 + j] = a3; }
    }
    __syncthreads();
    if (tid < 200) {
      float gi = sigm(a0 + pg[tid]);
      float gf = sigm(a1 + pg[200 + tid]);
      float gg = tanhf(a2 + pg[400 + tid]);
      float go = sigm(a3 + pg[600 + tid]);
      c_reg = gf * c_reg + gi * gg;
      float hv = go * tanhf(c_reg);
      xcat[tid] = hv;
      h2s[tid] = __builtin_bit_cast(u16, (f16)hv);
      if (!do_eta) hseq[t * 200 + tid] = hv;
    }
    __syncthreads();
    if (do_eta) {
      if (tid < 400) {
        const int k100 = tid >> 2, s4 = tid & 3;
        const float* Wr = (k100 < 50) ? (muW + k100 * 250) : (lsW + (k100 - 50) * 250);
        const float2* Wr2 = (const float2*)Wr;   // rows are 1000 B -> 8B aligned
        const float2* X2 = (const float2*)xcat;
        const int p0 = s4 * 32;
        const int p1 = min(125, p0 + 32);
        float p = 0.f;
        for (int q = p0; q < p1; ++q) { float2 w = Wr2[q]; float2 x = X2[q]; p += w.x * x.x + w.y * x.y; }
        pc[tid] = p;
      }
      __syncthreads();
      if (tid < 100) {
        float v = pc[tid * 4] + pc[tid * 4 + 1] + pc[tid * 4 + 2] + pc[tid * 4 + 3];
        v += (tid < 50) ? mub[tid] : lsb[tid - 50];
        mu_ls[tid] = v;
      }
      __syncthreads();
      if (tid < 50) {
        float mu = mu_ls[tid], ls = mu_ls[50 + tid], ep = xcat[200 + tid];
        float pls = (t == 0) ? 0.f : LOG_DELTA;
        float pv = __expf(pls) + 1e-6f;
        float d = mu - ep;
        klacc += 0.5f * ((__expf(ls) + d * d) / pv - 1.f + pls - ls);
        xcat[200 + tid] = mu;
        etas[t * 50 + tid] = mu;
      }
      __syncthreads();
    }
  }
  if (do_eta) {
    if (tid < 50) pg[tid] = klacc;
    __syncthreads();
    if (tid == 0) { float ss = 0.f; for (int i = 0; i < 50; ++i) ss += pg[i]; accum[0] = ss; }
  }
}

// ---------------- theta head: softmax + kl_theta ----------------

__global__ __launch_bounds__(64) void k_theta(const float* __restrict__ mu_t, const float* __restrict__ ls_t,
                                              const float* __restrict__ etas, const int* __restrict__ times,
                                              float* __restrict__ theta, float* __restrict__ accum) {
  const int b = blockIdx.x, lane = threadIdx.x;
  float m_ = 0.f, l_ = 0.f, e_ = 0.f, mx = -1e30f;
  if (lane < 50) {
    m_ = mu_t[b * 50 + lane];
    l_ = ls_t[b * 50 + lane];
    e_ = etas[times[b] * 50 + lane];
    mx = m_;
  }
  for (int o = 32; o > 0; o >>= 1) mx = fmaxf(mx, __shfl_down(mx, o));
  mx = __shfl(mx, 0);
  float ex = (lane < 50) ? __expf(m_ - mx) : 0.f;
  float sum = ex;
  for (int o = 32; o > 0; o >>= 1) sum += __shfl_down(sum, o);
  sum = __shfl(sum, 0);
  if (lane < 50) theta[b * 50 + lane] = ex / sum;
  float kl = 0.f;
  if (lane < 50) {
    float d = m_ - e_;
    kl = 0.5f * ((__expf(l_) + d * d) / (1.f + 1e-6f) - 1.f - l_);
  }
  for (int o = 32; o > 0; o >>= 1) kl += __shfl_down(kl, o);
  if (lane == 0) atomicAdd(accum + 1, kl);
}

// ---------------- softmax row stats over logits (bf16) ----------------

__global__ __launch_bounds__(256) void k_rowstats(const u16* __restrict__ logit, float2* __restrict__ stats) {
  const int r = blockIdx.x, tid = threadIdx.x;
  const u16* row = logit + (size_t)r * 10000;
  __shared__ float red[256];
  float mx = -1e30f;
  for (int v = tid; v < 10000; v += 256) mx = fmaxf(mx, bf2f(row[v]));
  red[tid] = mx; __syncthreads();
  for (int o = 128; o > 0; o >>= 1) { if (tid < o) red[tid] = fmaxf(red[tid], red[tid + o]); __syncthreads(); }
  const float M = red[0]; __syncthreads();
  float ssum = 0.f;
  for (int v = tid; v < 10000; v += 256) ssum += __expf(bf2f(row[v]) - M);
  red[tid] = ssum; __syncthreads();
  for (int o = 128; o > 0; o >>= 1) { if (tid < o) red[tid] += red[tid + o]; __syncthreads(); }
  if (tid == 0) stats[r] = make_float2(M, red[0]);
}

// ---------------- NLL ----------------

__global__ __launch_bounds__(256) void k_nll(const u16* __restrict__ logit, const float2* __restrict__ stats,
                                             const float* __restrict__ theta, const float* __restrict__ bows,
                                             const int* __restrict__ times, float* __restrict__ accum) {
  const int b = blockIdx.x, seg = blockIdx.y, tid = threadIdx.x;
  const int t = times[b];
  __shared__ float c2[52];
  __shared__ float red[256];
  if (tid < 50) {
    float2 mz = stats[t * 50 + tid];
    c2[tid] = theta[b * 50 + tid] / mz.y * __expf(-mz.x);
  }
  __syncthreads();
  float part = 0.f;
  const int v0 = seg * 1250, v1 = v0 + 1250;
  const u16* base = logit + (size_t)t * 500000;
  for (int v = v0 + tid; v < v1; v += 256) {
    float ssv = 1e-12f;
#pragma unroll
    for (int k = 0; k < 50; ++k) ssv += c2[k] * __expf(bf2f(base[k * 10000 + v]));
    part += bows[b * 10000 + v] * __logf(ssv);
  }
  red[tid] = part; __syncthreads();
  for (int o = 128; o > 0; o >>= 1) { if (tid < o) red[tid] += red[tid + o]; __syncthreads(); }
  if (tid == 0) atomicAdd(accum + 3, -red[0]);
}

// ---------------- kl_alpha ----------------

__global__ __launch_bounds__(256) void k_alpha_kl(const float* __restrict__ muq, const float* __restrict__ lsq,
                                                  float* __restrict__ accum) {
  __shared__ float red[256];
  const int tid = threadIdx.x;
  float s = 0.f;
  for (int i = blockIdx.x * 256 + tid; i < 1500000; i += gridDim.x * 256) {
    int r = i % 300;
    int tk = i / 300;
    int k = tk % 50;
    int t = tk / 50;
    size_t idx = (size_t)k * 30000 + (size_t)t * 300 + r;
    float mu = muq[idx], ls = lsq[idx];
    float pm = 0.f, pls = 0.f;
    if (t > 0) { pm = muq[idx - 300]; pls = LOG_DELTA; }
    float d = mu - pm;
    s += 0.5f * ((__expf(ls) + d * d) / (__expf(pls) + 1e-6f) - 1.f + pls - ls);
  }
  red[tid] = s; __syncthreads();
  for (int o = 128; o > 0; o >>= 1) { if (tid < o) red[tid] += red[tid + o]; __syncthreads(); }
  if (tid == 0) atomicAdd(accum + 2, red[0]);
}

// ---------------- final combine ----------------

__global__ __launch_bounds__(64) void k_final(const float* __restrict__ accum, float* __restrict__ out) {
  if (threadIdx.x == 0) {
    float nll = accum[3] * COEFF;
    float kl_eta = accum[0];
    float kl_theta = accum[1] * COEFF;
    float kl_alpha = accum[2];
    out[0] = nll + kl_eta + kl_theta + kl_alpha;
    out[1] = nll;
    out[2] = kl_eta;
    out[3] = kl_theta;
    out[4] = kl_alpha;
  }
}

// ---------------- launcher ----------------

extern "C" void kernel_launch(void* const* d_in, const int* in_sizes, int n_in,
                              void* d_out, int out_size, void* d_ws, size_t ws_size,
                              hipStream_t stream) {
  (void)in_sizes; (void)n_in; (void)out_size; (void)ws_size;
  const float* bows   = (const float*)d_in[0];
  const int*   times  = (const int*)d_in[1];
  const float* rnn_in = (const float*)d_in[2];
  const float* rho_W  = (const float*)d_in[3];
  const float* muq    = (const float*)d_in[4];
  const float* lsq    = (const float*)d_in[5];
  const float* qW1    = (const float*)d_in[6];
  const float* qb1    = (const float*)d_in[7];
  const float* qW2    = (const float*)d_in[8];
  const float* qb2    = (const float*)d_in[9];
  const float* muthW  = (const float*)d_in[10];
  const float* muthb  = (const float*)d_in[11];
  const float* lsthW  = (const float*)d_in[12];
  const float* lsthb  = (const float*)d_in[13];
  const float* emW    = (const float*)d_in[14];
  const float* emb    = (const float*)d_in[15];
  const float* Wih    = (const float*)d_in[16];
  const float* Whh    = (const float*)d_in[17];
  const float* bih    = (const float*)d_in[18];
  const float* bhh    = (const float*)d_in[19];
  const float* mueW   = (const float*)d_in[20];
  const float* mueb   = (const float*)d_in[21];
  const float* lseW   = (const float*)d_in[22];
  const float* lseb   = (const float*)d_in[23];
  float* out = (float*)d_out;
  float* ws = (float*)d_ws;

  // workspace layout (float offsets); total ~108 MB
  float* accum = ws + 0;                       // 8
  float* nb    = ws + 8;                       // 128*10000
  float* x0    = ws + 1280008;                 // 100*200
  float* xproj = ws + 1300008;                 // 100*800
  float* hsA   = ws + 1380008;                 // 100*200
  float* hsB   = ws + 1400008;                 // 100*200
  u16*   whhh  = (u16*)(ws + 1420008);         // 3*800*200 f16
  float* bsum  = ws + 1660008;                 // 3*800
  float* etas  = ws + 1662408;                 // 100*50
  float* h1    = ws + 1667408;                 // 128*800
  float* h2    = ws + 1769808;                 // 128*800
  float* mu_t  = ws + 1872208;                 // 128*50
  float* ls_t  = ws + 1878608;                 // 128*50
  float* theta = ws + 1885008;                 // 128*50
  float2* stats = (float2*)(ws + 1891408);     // 5000 float2
  u16*   logit = (u16*)(ws + 1901408);         // 5000*10000 bf16

  k_zero<<<1, 64, 0, stream>>>(accum);
  k_nb<<<128, 256, 0, stream>>>(bows, nb);
  k_cvt_f16<<<1875, 256, 0, stream>>>(Whh, whhh, 480000);
  k_bsum<<<10, 256, 0, stream>>>(bih, bhh, bsum, 2400);

  // x0 = rnn_inp @ eta_map_W^T + eta_map_b  (K-split, bias prefilled)
  k_fill<<<79, 256, 0, stream>>>(x0, emb, 200, 20000);
  gemm_abT<0, 5><<<dim3(1, 2, 16), 256, 0, stream>>>(rnn_in, emW, nullptr, x0, nullptr,
                                                     100, 200, 10000, 10000, 10000, nullptr, nullptr);

  // LSTM layers
  const float* lin[3] = {x0, hsA, hsB};
  float* lout[3] = {hsA, hsB, hsA};
  for (int l = 0; l < 3; ++l) {
    gemm_abT<0, 1><<<dim3(1, 7, 1), 256, 0, stream>>>(lin[l], Wih + l * 160000, bsum + l * 800,
                                                      xproj, nullptr, 100, 800, 200, 200, 200,
                                                      nullptr, nullptr);
    lstm_scan<<<1, 512, 0, stream>>>(whhh + l * 160000, xproj, lout[l],
                                     mueW, mueb, lseW, lseb, etas, accum, (l == 2) ? 1 : 0);
  }

  // theta encoder
  k_fill<<<400, 256, 0, stream>>>(h1, qb1, 800, 102400);
  gemm_abT<2, 5><<<dim3(1, 7, 8), 256, 0, stream>>>(nb, qW1, nullptr, h1, nullptr,
                                                    128, 800, 10050, 10000, 10050, times, etas);
  k_relu<<<400, 256, 0, stream>>>(h1, 102400);
  gemm_abT<0, 2><<<dim3(1, 7, 1), 256, 0, stream>>>(h1, qW2, qb2, h2, nullptr,
                                                    128, 800, 800, 800, 800, nullptr, nullptr);
  gemm_abT<0, 1><<<dim3(1, 1, 1), 256, 0, stream>>>(h2, muthW, muthb, mu_t, nullptr,
                                                    128, 50, 800, 800, 800, nullptr, nullptr);
  gemm_abT<0, 1><<<dim3(1, 1, 1), 256, 0, stream>>>(h2, lsthW, lsthb, ls_t, nullptr,
                                                    128, 50, 800, 800, 800, nullptr, nullptr);
  k_theta<<<128, 64, 0, stream>>>(mu_t, ls_t, etas, times, theta, accum);

  // beta logits (bf16) + softmax stats + NLL
  gemm_abT<1, 3><<<dim3(40, 79, 1), 256, 0, stream>>>(muq, rho_W, nullptr, nullptr, logit,
                                                      5000, 10000, 300, 300, 300, nullptr, nullptr);
  k_rowstats<<<5000, 256, 0, stream>>>(logit, stats);
  k_nll<<<dim3(128, 8), 256, 0, stream>>>(logit, stats, theta, bows, times, accum);

  k_alpha_kl<<<512, 256, 0, stream>>>(muq, lsq, accum);
  k_final<<<1, 64, 0, stream>>>(accum, out);
}

// Round 2
// 3941.158 us; speedup vs baseline: 1.5886x; 1.5886x over previous
//
#include <hip/hip_runtime.h>

// DETM forward. Round 2: VGPR-resident LSTM weights.
//   R1 post-mortem: lstm_scan was single-CU L2-BW bound (9.1 B/cy weight
//   re-stream per step). Fix: 400 threads hold Whh in registers (200 VGPRs
//   each), LDS broadcast of h, fully unrolled fdot2.
// Output: 5 floats = loss, nll, kl_eta, kl_theta, kl_alpha.

typedef unsigned int u32;
typedef unsigned short u16;
typedef _Float16 f16;
typedef f16 f16x2 __attribute__((ext_vector_type(2)));

#define LOG_DELTA (-5.2983174f)
#define COEFF 781.25f   // TRAIN_SIZE / B = 100000/128

__device__ __forceinline__ float bf2f(u16 a) { return __uint_as_float(((u32)a) << 16); }
__device__ __forceinline__ u16 f2bf(float f) {
  u32 u = __float_as_uint(f);
  u32 r = (u + 0x7fffu + ((u >> 16) & 1u)) >> 16;
  return (u16)r;
}
__device__ __forceinline__ float fdot2(u32 w, u32 h, float acc) {
  return __builtin_amdgcn_fdot2(__builtin_bit_cast(f16x2, w), __builtin_bit_cast(f16x2, h), acc, false);
}
__device__ __forceinline__ float sigm(float x) { return 1.f / (1.f + __expf(-x)); }

// ---------------- small utility kernels ----------------

__global__ __launch_bounds__(64) void k_zero(float* __restrict__ accum) {
  if (threadIdx.x < 8) accum[threadIdx.x] = 0.f;
}

__global__ __launch_bounds__(256) void k_nb(const float* __restrict__ bows, float* __restrict__ nb) {
  __shared__ float red[256];
  const int b = blockIdx.x, tid = threadIdx.x;
  float s = 0.f;
  for (int v = tid; v < 10000; v += 256) s += bows[b * 10000 + v];
  red[tid] = s; __syncthreads();
  for (int o = 128; o > 0; o >>= 1) { if (tid < o) red[tid] += red[tid + o]; __syncthreads(); }
  const float inv = 1.f / red[0];
  for (int v = tid; v < 10000; v += 256) nb[b * 10000 + v] = bows[b * 10000 + v] * inv;
}

__global__ __launch_bounds__(256) void k_cvt_f16(const float* __restrict__ w, u16* __restrict__ out, int n) {
  int i = blockIdx.x * 256 + threadIdx.x;
  if (i < n) { f16 h = (f16)w[i]; out[i] = __builtin_bit_cast(u16, h); }
}

__global__ __launch_bounds__(256) void k_bsum(const float* __restrict__ a, const float* __restrict__ b,
                                              float* __restrict__ o, int n) {
  int i = blockIdx.x * 256 + threadIdx.x;
  if (i < n) o[i] = a[i] + b[i];
}

__global__ __launch_bounds__(256) void k_fill(float* __restrict__ C, const float* __restrict__ bias,
                                              int N, int total) {
  for (int i = blockIdx.x * 256 + threadIdx.x; i < total; i += gridDim.x * 256)
    C[i] = bias[i % N];
}

__global__ __launch_bounds__(256) void k_relu(float* __restrict__ C, int total) {
  for (int i = blockIdx.x * 256 + threadIdx.x; i < total; i += gridDim.x * 256) {
    float v = C[i];
    C[i] = v > 0.f ? v : 0.f;
  }
}

// ---------------- generic fp32 GEMM: C[M,N] = A[M,K] @ B[N,K]^T ----------------

#define GT 128
#define GBK 16

template<int AMODE, int EPI>
__global__ __launch_bounds__(256) void gemm_abT(
    const float* __restrict__ A, const float* __restrict__ Bm,
    const float* __restrict__ bias, float* __restrict__ C, u16* __restrict__ Cb,
    int M, int N, int Kd, int lda, int ldb,
    const int* __restrict__ times, const float* __restrict__ etas)
{
  __shared__ __align__(16) float As[GBK][GT + 4];
  __shared__ __align__(16) float Bs[GBK][GT + 4];
  const int tid = threadIdx.x;
  const int tx = tid & 15, ty = tid >> 4;
  const int m_base = blockIdx.x * GT, n_base = blockIdx.y * GT;
  float acc[8][8] = {};
  const int nkt = (Kd + GBK - 1) / GBK;
  const int per = (nkt + gridDim.z - 1) / gridDim.z;
  const int kt0 = blockIdx.z * per;
  const int kt1 = min(nkt, kt0 + per);
  const int lkk = tid & 15;
  const int lmm = tid >> 4;
  for (int kt = kt0; kt < kt1; ++kt) {
    const int kg = kt * GBK + lkk;
#pragma unroll
    for (int i = 0; i < 8; ++i) {
      int m = m_base + lmm + i * 16;
      float v = 0.f;
      if (m < M && kg < Kd) {
        if (AMODE == 0) v = A[(size_t)m * lda + kg];
        else if (AMODE == 1) { int tt = m / 50; int k2 = m - tt * 50; v = A[k2 * 30000 + tt * 300 + kg]; }
        else {
          if (kg < 10000) v = A[(size_t)m * 10000 + kg];
          else v = etas[times[m] * 50 + (kg - 10000)];
        }
      }
      As[lkk][lmm + i * 16] = v;
    }
#pragma unroll
    for (int i = 0; i < 8; ++i) {
      int n = n_base + lmm + i * 16;
      float v = 0.f;
      if (n < N && kg < Kd) v = Bm[(size_t)n * ldb + kg];
      Bs[lkk][lmm + i * 16] = v;
    }
    __syncthreads();
#pragma unroll
    for (int kk = 0; kk < GBK; ++kk) {
      const float4* ap = (const float4*)&As[kk][ty * 8];
      const float4* bp = (const float4*)&Bs[kk][tx * 8];
      float4 a0 = ap[0], a1 = ap[1];
      float4 b0 = bp[0], b1 = bp[1];
      float av[8] = {a0.x, a0.y, a0.z, a0.w, a1.x, a1.y, a1.z, a1.w};
      float bv[8] = {b0.x, b0.y, b0.z, b0.w, b1.x, b1.y, b1.z, b1.w};
#pragma unroll
      for (int i = 0; i < 8; ++i)
#pragma unroll
        for (int j = 0; j < 8; ++j) acc[i][j] += av[i] * bv[j];
    }
    __syncthreads();
  }
#pragma unroll
  for (int i = 0; i < 8; ++i) {
    int m = m_base + ty * 8 + i;
    if (m >= M) continue;
#pragma unroll
    for (int j = 0; j < 8; ++j) {
      int n = n_base + tx * 8 + j;
      if (n >= N) continue;
      float v = acc[i][j];
      if (EPI == 1) { C[(size_t)m * N + n] = v + bias[n]; }
      else if (EPI == 2) { v += bias[n]; C[(size_t)m * N + n] = v > 0.f ? v : 0.f; }
      else if (EPI == 3) { Cb[(size_t)m * N + n] = f2bf(v); }
      else if (EPI == 5) { atomicAdd(&C[(size_t)m * N + n], v); }
      else { C[(size_t)m * N + n] = v; }
    }
  }
}

// ---------------- sequential LSTM layer scan, VGPR-resident weights ----------------
// 448 threads (7 waves); threads 0..399 active for dots.
//   thread j    (j<200): rows j (i-gate)     and 400+j (g-gate)
//   thread 200+j       : rows 200+j (f-gate) and 600+j (o-gate)
// Each thread holds its 2 rows of Whh as 50 uint4 (200 VGPRs, f16).
// h broadcast via LDS (f16x2 packed). xproj added at accumulation end so its
// global load latency hides under the dot phase.

__global__ __launch_bounds__(448, 2) void lstm_scan_reg(
    const u16* __restrict__ whh_h,   // 800*200 f16 (this layer)
    const float* __restrict__ xproj, // [100][800] = Wih@x + bih + bhh
    float* __restrict__ hseq,        // [100][200] output (unused if do_eta)
    const float* __restrict__ muW, const float* __restrict__ mub,
    const float* __restrict__ lsW, const float* __restrict__ lsb,
    float* __restrict__ etas, float* __restrict__ accum, const int do_eta)
{
  __shared__ __align__(16) u32 xh2[104];     // h as packed f16x2 (100 used)
  __shared__ __align__(16) float xcat[252];  // [0..199]=h f32, [200..249]=eta_prev
  __shared__ float ldsF[200];
  __shared__ float ldsO[200];
  __shared__ float pc[400];
  __shared__ float mu_ls[100];
  const int tid = threadIdx.x;
  const int act = (tid < 400);
  const int s = (tid >= 200) ? 1 : 0;
  const int j = tid - s * 200;               // hidden-unit index (valid for act)
  const int rowA = s ? (200 + j) : j;        // f : i
  const int rowB = s ? (600 + j) : (400 + j);// o : g
  uint4 wA[25], wB[25];
  if (act) {
    const uint4* W4 = (const uint4*)whh_h;   // 25 uint4 per row
#pragma unroll
    for (int c = 0; c < 25; ++c) { wA[c] = W4[rowA * 25 + c]; wB[c] = W4[rowB * 25 + c]; }
  }
  if (tid < 104) xh2[tid] = 0u;
  if (tid < 252) xcat[tid] = 0.f;
  float c_reg = 0.f, klacc = 0.f;
  __syncthreads();
  for (int t = 0; t < 100; ++t) {
    float accA = 0.f, accB = 0.f;
    if (act) {
      const float xA = xproj[t * 800 + rowA];   // issued early, used at end
      const float xB = xproj[t * 800 + rowB];
      float a0 = 0.f, a1 = 0.f, b0 = 0.f, b1 = 0.f;  // split dep chains
      const uint4* H4 = (const uint4*)xh2;
#pragma unroll
      for (int c = 0; c < 25; ++c) {
        uint4 hv = H4[c];
        if (c & 1) {
          a1 = fdot2(wA[c].x, hv.x, a1); a1 = fdot2(wA[c].y, hv.y, a1);
          a1 = fdot2(wA[c].z, hv.z, a1); a1 = fdot2(wA[c].w, hv.w, a1);
          b1 = fdot2(wB[c].x, hv.x, b1); b1 = fdot2(wB[c].y, hv.y, b1);
          b1 = fdot2(wB[c].z, hv.z, b1); b1 = fdot2(wB[c].w, hv.w, b1);
        } else {
          a0 = fdot2(wA[c].x, hv.x, a0); a0 = fdot2(wA[c].y, hv.y, a0);
          a0 = fdot2(wA[c].z, hv.z, a0); a0 = fdot2(wA[c].w, hv.w, a0);
          b0 = fdot2(wB[c].x, hv.x, b0); b0 = fdot2(wB[c].y, hv.y, b0);
          b0 = fdot2(wB[c].z, hv.z, b0); b0 = fdot2(wB[c].w, hv.w, b0);
        }
      }
      accA = a0 + a1 + xA;
      accB = b0 + b1 + xB;
      if (s) { ldsF[j] = accA; ldsO[j] = accB; }
    }
    __syncthreads();   // gates visible; all dots done reading old h
    if (tid < 200) {
      float gi = sigm(accA);
      float gf = sigm(ldsF[j]);
      float gg = tanhf(accB);
      float go = sigm(ldsO[j]);
      c_reg = gf * c_reg + gi * gg;
      float hv = go * tanhf(c_reg);
      xcat[j] = hv;
      ((u16*)xh2)[j] = __builtin_bit_cast(u16, (f16)hv);
      if (!do_eta) hseq[t * 200 + j] = hv;
    }
    __syncthreads();   // new h visible for next step / eta matvec
    if (do_eta) {
      if (tid < 400) {
        const int k100 = tid >> 2, s4 = tid & 3;
        const float* Wr = (k100 < 50) ? (muW + k100 * 250) : (lsW + (k100 - 50) * 250);
        const float2* Wr2 = (const float2*)Wr;
        const float2* X2 = (const float2*)xcat;
        const int p0 = s4 * 32;
        const int p1 = min(125, p0 + 32);
        float p = 0.f;
        for (int q = p0; q < p1; ++q) { float2 w = Wr2[q]; float2 x = X2[q]; p += w.x * x.x + w.y * x.y; }
        pc[tid] = p;
      }
      __syncthreads();
      if (tid < 100) {
        float v = pc[tid * 4] + pc[tid * 4 + 1] + pc[tid * 4 + 2] + pc[tid * 4 + 3];
        v += (tid < 50) ? mub[tid] : lsb[tid - 50];
        mu_ls[tid] = v;
      }
      __syncthreads();
      if (tid < 50) {
        float mu = mu_ls[tid], ls = mu_ls[50 + tid], ep = xcat[200 + tid];
        float pls = (t == 0) ? 0.f : LOG_DELTA;
        float pv = __expf(pls) + 1e-6f;
        float d = mu - ep;
        klacc += 0.5f * ((__expf(ls) + d * d) / pv - 1.f + pls - ls);
        xcat[200 + tid] = mu;
        etas[t * 50 + tid] = mu;
      }
      __syncthreads();
    }
  }
  if (do_eta) {
    if (tid < 50) ldsF[tid] = klacc;
    __syncthreads();
    if (tid == 0) { float ss = 0.f; for (int i = 0; i < 50; ++i) ss += ldsF[i]; accum[0] = ss; }
  }
}

// ---------------- theta head: softmax + kl_theta ----------------

__global__ __launch_bounds__(64) void k_theta(const float* __restrict__ mu_t, const float* __restrict__ ls_t,
                                              const float* __restrict__ etas, const int* __restrict__ times,
                                              float* __restrict__ theta, float* __restrict__ accum) {
  const int b = blockIdx.x, lane = threadIdx.x;
  float m_ = 0.f, l_ = 0.f, e_ = 0.f, mx = -1e30f;
  if (lane < 50) {
    m_ = mu_t[b * 50 + lane];
    l_ = ls_t[b * 50 + lane];
    e_ = etas[times[b] * 50 + lane];
    mx = m_;
  }
  for (int o = 32; o > 0; o >>= 1) mx = fmaxf(mx, __shfl_down(mx, o));
  mx = __shfl(mx, 0);
  float ex = (lane < 50) ? __expf(m_ - mx) : 0.f;
  float sum = ex;
  for (int o = 32; o > 0; o >>= 1) sum += __shfl_down(sum, o);
  sum = __shfl(sum, 0);
  if (lane < 50) theta[b * 50 + lane] = ex / sum;
  float kl = 0.f;
  if (lane < 50) {
    float d = m_ - e_;
    kl = 0.5f * ((__expf(l_) + d * d) / (1.f + 1e-6f) - 1.f - l_);
  }
  for (int o = 32; o > 0; o >>= 1) kl += __shfl_down(kl, o);
  if (lane == 0) atomicAdd(accum + 1, kl);
}

// ---------------- softmax row stats over logits (bf16) ----------------

__global__ __launch_bounds__(256) void k_rowstats(const u16* __restrict__ logit, float2* __restrict__ stats) {
  const int r = blockIdx.x, tid = threadIdx.x;
  const u16* row = logit + (size_t)r * 10000;
  __shared__ float red[256];
  float mx = -1e30f;
  for (int v = tid; v < 10000; v += 256) mx = fmaxf(mx, bf2f(row[v]));
  red[tid] = mx; __syncthreads();
  for (int o = 128; o > 0; o >>= 1) { if (tid < o) red[tid] = fmaxf(red[tid], red[tid + o]); __syncthreads(); }
  const float M = red[0]; __syncthreads();
  float ssum = 0.f;
  for (int v = tid; v < 10000; v += 256) ssum += __expf(bf2f(row[v]) - M);
  red[tid] = ssum; __syncthreads();
  for (int o = 128; o > 0; o >>= 1) { if (tid < o) red[tid] += red[tid + o]; __syncthreads(); }
  if (tid == 0) stats[r] = make_float2(M, red[0]);
}

// ---------------- NLL ----------------

__global__ __launch_bounds__(256) void k_nll(const u16* __restrict__ logit, const float2* __restrict__ stats,
                                             const float* __restrict__ theta, const float* __restrict__ bows,
                                             const int* __restrict__ times, float* __restrict__ accum) {
  const int b = blockIdx.x, seg = blockIdx.y, tid = threadIdx.x;
  const int t = times[b];
  __shared__ float c2[52];
  __shared__ float red[256];
  if (tid < 50) {
    float2 mz = stats[t * 50 + tid];
    c2[tid] = theta[b * 50 + tid] / mz.y * __expf(-mz.x);
  }
  __syncthreads();
  float part = 0.f;
  const int v0 = seg * 1250, v1 = v0 + 1250;
  const u16* base = logit + (size_t)t * 500000;
  for (int v = v0 + tid; v < v1; v += 256) {
    float ssv = 1e-12f;
#pragma unroll
    for (int k = 0; k < 50; ++k) ssv += c2[k] * __expf(bf2f(base[k * 10000 + v]));
    part += bows[b * 10000 + v] * __logf(ssv);
  }
  red[tid] = part; __syncthreads();
  for (int o = 128; o > 0; o >>= 1) { if (tid < o) red[tid] += red[tid + o]; __syncthreads(); }
  if (tid == 0) atomicAdd(accum + 3, -red[0]);
}

// ---------------- kl_alpha ----------------

__global__ __launch_bounds__(256) void k_alpha_kl(const float* __restrict__ muq, const float* __restrict__ lsq,
                                                  float* __restrict__ accum) {
  __shared__ float red[256];
  const int tid = threadIdx.x;
  float s = 0.f;
  for (int i = blockIdx.x * 256 + tid; i < 1500000; i += gridDim.x * 256) {
    int r = i % 300;
    int tk = i / 300;
    int k = tk % 50;
    int t = tk / 50;
    size_t idx = (size_t)k * 30000 + (size_t)t * 300 + r;
    float mu = muq[idx], ls = lsq[idx];
    float pm = 0.f, pls = 0.f;
    if (t > 0) { pm = muq[idx - 300]; pls = LOG_DELTA; }
    float d = mu - pm;
    s += 0.5f * ((__expf(ls) + d * d) / (__expf(pls) + 1e-6f) - 1.f + pls - ls);
  }
  red[tid] = s; __syncthreads();
  for (int o = 128; o > 0; o >>= 1) { if (tid < o) red[tid] += red[tid + o]; __syncthreads(); }
  if (tid == 0) atomicAdd(accum + 2, red[0]);
}

// ---------------- final combine ----------------

__global__ __launch_bounds__(64) void k_final(const float* __restrict__ accum, float* __restrict__ out) {
  if (threadIdx.x == 0) {
    float nll = accum[3] * COEFF;
    float kl_eta = accum[0];
    float kl_theta = accum[1] * COEFF;
    float kl_alpha = accum[2];
    out[0] = nll + kl_eta + kl_theta + kl_alpha;
    out[1] = nll;
    out[2] = kl_eta;
    out[3] = kl_theta;
    out[4] = kl_alpha;
  }
}

// ---------------- launcher ----------------

extern "C" void kernel_launch(void* const* d_in, const int* in_sizes, int n_in,
                              void* d_out, int out_size, void* d_ws, size_t ws_size,
                              hipStream_t stream) {
  (void)in_sizes; (void)n_in; (void)out_size; (void)ws_size;
  const float* bows   = (const float*)d_in[0];
  const int*   times  = (const int*)d_in[1];
  const float* rnn_in = (const float*)d_in[2];
  const float* rho_W  = (const float*)d_in[3];
  const float* muq    = (const float*)d_in[4];
  const float* lsq    = (const float*)d_in[5];
  const float* qW1    = (const float*)d_in[6];
  const float* qb1    = (const float*)d_in[7];
  const float* qW2    = (const float*)d_in[8];
  const float* qb2    = (const float*)d_in[9];
  const float* muthW  = (const float*)d_in[10];
  const float* muthb  = (const float*)d_in[11];
  const float* lsthW  = (const float*)d_in[12];
  const float* lsthb  = (const float*)d_in[13];
  const float* emW    = (const float*)d_in[14];
  const float* emb    = (const float*)d_in[15];
  const float* Wih    = (const float*)d_in[16];
  const float* Whh    = (const float*)d_in[17];
  const float* bih    = (const float*)d_in[18];
  const float* bhh    = (const float*)d_in[19];
  const float* mueW   = (const float*)d_in[20];
  const float* mueb   = (const float*)d_in[21];
  const float* lseW   = (const float*)d_in[22];
  const float* lseb   = (const float*)d_in[23];
  float* out = (float*)d_out;
  float* ws = (float*)d_ws;

  // workspace layout (float offsets); total ~108 MB
  float* accum = ws + 0;                       // 8
  float* nb    = ws + 8;                       // 128*10000
  float* x0    = ws + 1280008;                 // 100*200
  float* xproj = ws + 1300008;                 // 100*800
  float* hsA   = ws + 1380008;                 // 100*200
  float* hsB   = ws + 1400008;                 // 100*200
  u16*   whhh  = (u16*)(ws + 1420008);         // 3*800*200 f16
  float* bsum  = ws + 1660008;                 // 3*800
  float* etas  = ws + 1662408;                 // 100*50
  float* h1    = ws + 1667408;                 // 128*800
  float* h2    = ws + 1769808;                 // 128*800
  float* mu_t  = ws + 1872208;                 // 128*50
  float* ls_t  = ws + 1878608;                 // 128*50
  float* theta = ws + 1885008;                 // 128*50
  float2* stats = (float2*)(ws + 1891408);     // 5000 float2
  u16*   logit = (u16*)(ws + 1901408);         // 5000*10000 bf16

  k_zero<<<1, 64, 0, stream>>>(accum);
  k_nb<<<128, 256, 0, stream>>>(bows, nb);
  k_cvt_f16<<<1875, 256, 0, stream>>>(Whh, whhh, 480000);
  k_bsum<<<10, 256, 0, stream>>>(bih, bhh, bsum, 2400);

  // x0 = rnn_inp @ eta_map_W^T + eta_map_b  (K-split, bias prefilled)
  k_fill<<<79, 256, 0, stream>>>(x0, emb, 200, 20000);
  gemm_abT<0, 5><<<dim3(1, 2, 16), 256, 0, stream>>>(rnn_in, emW, nullptr, x0, nullptr,
                                                     100, 200, 10000, 10000, 10000, nullptr, nullptr);

  // LSTM layers
  const float* lin[3] = {x0, hsA, hsB};
  float* lout[3] = {hsA, hsB, hsA};
  for (int l = 0; l < 3; ++l) {
    gemm_abT<0, 1><<<dim3(1, 7, 1), 256, 0, stream>>>(lin[l], Wih + l * 160000, bsum + l * 800,
                                                      xproj, nullptr, 100, 800, 200, 200, 200,
                                                      nullptr, nullptr);
    lstm_scan_reg<<<1, 448, 0, stream>>>(whhh + l * 160000, xproj, lout[l],
                                         mueW, mueb, lseW, lseb, etas, accum, (l == 2) ? 1 : 0);
  }

  // theta encoder
  k_fill<<<400, 256, 0, stream>>>(h1, qb1, 800, 102400);
  gemm_abT<2, 5><<<dim3(1, 7, 8), 256, 0, stream>>>(nb, qW1, nullptr, h1, nullptr,
                                                    128, 800, 10050, 10000, 10050, times, etas);
  k_relu<<<400, 256, 0, stream>>>(h1, 102400);
  gemm_abT<0, 2><<<dim3(1, 7, 1), 256, 0, stream>>>(h1, qW2, qb2, h2, nullptr,
                                                    128, 800, 800, 800, 800, nullptr, nullptr);
  gemm_abT<0, 1><<<dim3(1, 1, 1), 256, 0, stream>>>(h2, muthW, muthb, mu_t, nullptr,
                                                    128, 50, 800, 800, 800, nullptr, nullptr);
  gemm_abT<0, 1><<<dim3(1, 1, 1), 256, 0, stream>>>(h2, lsthW, lsthb, ls_t, nullptr,
                                                    128, 50, 800, 800, 800, nullptr, nullptr);
  k_theta<<<128, 64, 0, stream>>>(mu_t, ls_t, etas, times, theta, accum);

  // beta logits (bf16) + softmax stats + NLL
  gemm_abT<1, 3><<<dim3(40, 79, 1), 256, 0, stream>>>(muq, rho_W, nullptr, nullptr, logit,
                                                      5000, 10000, 300, 300, 300, nullptr, nullptr);
  k_rowstats<<<5000, 256, 0, stream>>>(logit, stats);
  k_nll<<<dim3(128, 8), 256, 0, stream>>>(logit, stats, theta, bows, times, accum);

  k_alpha_kl<<<512, 256, 0, stream>>>(muq, lsq, accum);
  k_final<<<1, 64, 0, stream>>>(accum, out);
}

// Round 3
// 2699.637 us; speedup vs baseline: 2.3191x; 1.4599x over previous
//
#include <hip/hip_runtime.h>

// DETM forward. Round 3:
//   - beta GEMM -> bf16 MFMA (m97 structure: global_load_lds w=16, 128x128 tile)
//   - lstm: 512 thr, sched_barrier-fenced dot groups to cap VGPR pressure (anti-spill)
//   - softmax max-pass dropped (logits ~O(1)); rowsum only
//   - qtheta GEMM K-split 8->24

typedef unsigned int u32;
typedef unsigned short u16;
typedef _Float16 f16;
typedef f16 f16x2 __attribute__((ext_vector_type(2)));
typedef short bf16x8 __attribute__((ext_vector_type(8)));
typedef float f32x4 __attribute__((ext_vector_type(4)));

#define LOG_DELTA (-5.2983174f)
#define COEFF 781.25f   // TRAIN_SIZE / B

__device__ __forceinline__ float bf2f(u16 a) { return __uint_as_float(((u32)a) << 16); }
__device__ __forceinline__ u16 f2bf(float f) {
  u32 u = __float_as_uint(f);
  u32 r = (u + 0x7fffu + ((u >> 16) & 1u)) >> 16;
  return (u16)r;
}
__device__ __forceinline__ float fdot2(u32 w, u32 h, float acc) {
  return __builtin_amdgcn_fdot2(__builtin_bit_cast(f16x2, w), __builtin_bit_cast(f16x2, h), acc, false);
}
__device__ __forceinline__ float sigm(float x) { return 1.f / (1.f + __expf(-x)); }
__device__ __forceinline__ float ftanh(float x) { float t = __expf(2.f * x); return (t - 1.f) / (t + 1.f); }
__device__ __forceinline__ void async_load16(const u16* g, u16* l) {
  __builtin_amdgcn_global_load_lds((const __attribute__((address_space(1))) u32*)g,
                                   (__attribute__((address_space(3))) u32*)l, 16, 0, 0);
}

// ---------------- small utility kernels ----------------

__global__ __launch_bounds__(64) void k_zero(float* __restrict__ accum) {
  if (threadIdx.x < 8) accum[threadIdx.x] = 0.f;
}

__global__ __launch_bounds__(256) void k_nb(const float* __restrict__ bows, float* __restrict__ nb) {
  __shared__ float red[256];
  const int b = blockIdx.x, tid = threadIdx.x;
  float s = 0.f;
  for (int v = tid; v < 10000; v += 256) s += bows[b * 10000 + v];
  red[tid] = s; __syncthreads();
  for (int o = 128; o > 0; o >>= 1) { if (tid < o) red[tid] += red[tid + o]; __syncthreads(); }
  const float inv = 1.f / red[0];
  for (int v = tid; v < 10000; v += 256) nb[b * 10000 + v] = bows[b * 10000 + v] * inv;
}

__global__ __launch_bounds__(256) void k_cvt_f16(const float* __restrict__ w, u16* __restrict__ out, int n) {
  int i = blockIdx.x * 256 + threadIdx.x;
  if (i < n) { f16 h = (f16)w[i]; out[i] = __builtin_bit_cast(u16, h); }
}

__global__ __launch_bounds__(256) void k_bsum(const float* __restrict__ a, const float* __restrict__ b,
                                              float* __restrict__ o, int n) {
  int i = blockIdx.x * 256 + threadIdx.x;
  if (i < n) o[i] = a[i] + b[i];
}

__global__ __launch_bounds__(256) void k_fill(float* __restrict__ C, const float* __restrict__ bias,
                                              int N, int total) {
  for (int i = blockIdx.x * 256 + threadIdx.x; i < total; i += gridDim.x * 256)
    C[i] = bias[i % N];
}

__global__ __launch_bounds__(256) void k_relu(float* __restrict__ C, int total) {
  for (int i = blockIdx.x * 256 + threadIdx.x; i < total; i += gridDim.x * 256) {
    float v = C[i];
    C[i] = v > 0.f ? v : 0.f;
  }
}

// bf16 staging for the beta MFMA GEMM. A: alphas [5120][320] (row m=t*50+k), B: rho [10112][320]
__global__ __launch_bounds__(256) void k_prep_A(const float* __restrict__ muq, u16* __restrict__ Abf) {
  int idx = blockIdx.x * 256 + threadIdx.x;
  if (idx >= 5120 * 320) return;
  int r = idx % 320, m = idx / 320;
  float v = 0.f;
  if (r < 300 && m < 5000) { int t = m / 50, k = m - t * 50; v = muq[k * 30000 + t * 300 + r]; }
  Abf[idx] = f2bf(v);
}
__global__ __launch_bounds__(256) void k_prep_B(const float* __restrict__ rho, u16* __restrict__ Bbf) {
  int idx = blockIdx.x * 256 + threadIdx.x;
  if (idx >= 10112 * 320) return;
  int r = idx % 320, n = idx / 320;
  float v = (r < 300 && n < 10000) ? rho[n * 300 + r] : 0.f;
  Bbf[idx] = f2bf(v);
}

// ---------------- generic fp32 GEMM (small/medium mats): C[M,N] = A[M,K] @ B[N,K]^T ----------------

#define GT 128
#define GBK 16

template<int AMODE, int EPI>
__global__ __launch_bounds__(256) void gemm_abT(
    const float* __restrict__ A, const float* __restrict__ Bm,
    const float* __restrict__ bias, float* __restrict__ C,
    int M, int N, int Kd, int lda, int ldb,
    const int* __restrict__ times, const float* __restrict__ etas)
{
  __shared__ __align__(16) float As[GBK][GT + 4];
  __shared__ __align__(16) float Bs[GBK][GT + 4];
  const int tid = threadIdx.x;
  const int tx = tid & 15, ty = tid >> 4;
  const int m_base = blockIdx.x * GT, n_base = blockIdx.y * GT;
  float acc[8][8] = {};
  const int nkt = (Kd + GBK - 1) / GBK;
  const int per = (nkt + gridDim.z - 1) / gridDim.z;
  const int kt0 = blockIdx.z * per;
  const int kt1 = min(nkt, kt0 + per);
  const int lkk = tid & 15;
  const int lmm = tid >> 4;
  for (int kt = kt0; kt < kt1; ++kt) {
    const int kg = kt * GBK + lkk;
#pragma unroll
    for (int i = 0; i < 8; ++i) {
      int m = m_base + lmm + i * 16;
      float v = 0.f;
      if (m < M && kg < Kd) {
        if (AMODE == 0) v = A[(size_t)m * lda + kg];
        else {
          if (kg < 10000) v = A[(size_t)m * 10000 + kg];
          else v = etas[times[m] * 50 + (kg - 10000)];
        }
      }
      As[lkk][lmm + i * 16] = v;
    }
#pragma unroll
    for (int i = 0; i < 8; ++i) {
      int n = n_base + lmm + i * 16;
      float v = 0.f;
      if (n < N && kg < Kd) v = Bm[(size_t)n * ldb + kg];
      Bs[lkk][lmm + i * 16] = v;
    }
    __syncthreads();
#pragma unroll
    for (int kk = 0; kk < GBK; ++kk) {
      const float4* ap = (const float4*)&As[kk][ty * 8];
      const float4* bp = (const float4*)&Bs[kk][tx * 8];
      float4 a0 = ap[0], a1 = ap[1];
      float4 b0 = bp[0], b1 = bp[1];
      float av[8] = {a0.x, a0.y, a0.z, a0.w, a1.x, a1.y, a1.z, a1.w};
      float bv[8] = {b0.x, b0.y, b0.z, b0.w, b1.x, b1.y, b1.z, b1.w};
#pragma unroll
      for (int i = 0; i < 8; ++i)
#pragma unroll
        for (int j = 0; j < 8; ++j) acc[i][j] += av[i] * bv[j];
    }
    __syncthreads();
  }
#pragma unroll
  for (int i = 0; i < 8; ++i) {
    int m = m_base + ty * 8 + i;
    if (m >= M) continue;
#pragma unroll
    for (int j = 0; j < 8; ++j) {
      int n = n_base + tx * 8 + j;
      if (n >= N) continue;
      float v = acc[i][j];
      if (EPI == 1) { C[(size_t)m * N + n] = v + bias[n]; }
      else if (EPI == 2) { v += bias[n]; C[(size_t)m * N + n] = v > 0.f ? v : 0.f; }
      else if (EPI == 5) { atomicAdd(&C[(size_t)m * N + n], v); }
      else { C[(size_t)m * N + n] = v; }
    }
  }
}

// ---------------- beta GEMM: bf16 MFMA, C[M,N](bf16) = A[M,320] @ B[N,320]^T ----------------
// m97 structure: 128x128 tile, BK=32, global_load_lds w=16, 2x2 waves x 4x4 16x16x32 frags.

__global__ __launch_bounds__(256) void gemm_mfma_bT(
    const u16* __restrict__ A, const u16* __restrict__ B, u16* __restrict__ C,
    int M, int N)
{
  __shared__ u16 As[128 * 32];
  __shared__ u16 Bs[128 * 32];
  const int tid = threadIdx.x;
  const int l = tid & 63, w = tid >> 6;
  const int wm = w & 1, wn = w >> 1;
  const int m0 = blockIdx.x * 128, n0 = blockIdx.y * 128;
  f32x4 acc[4][4] = {};
  const int arow = l >> 2;          // row within 16-row chunk
  const int acol = (l & 3) * 8;     // u16 col offset within BK
  for (int kt = 0; kt < 10; ++kt) {
    const int k0 = kt * 32;
#pragma unroll
    for (int c = 0; c < 2; ++c) {
      const int i = w + c * 4;      // chunk 0..7
      async_load16(A + (size_t)(m0 + i * 16 + arow) * 320 + k0 + acol, As + i * 512);
      async_load16(B + (size_t)(n0 + i * 16 + arow) * 320 + k0 + acol, Bs + i * 512);
    }
    __syncthreads();
    bf16x8 af[4], bfr[4];
#pragma unroll
    for (int x = 0; x < 4; ++x) {
      af[x]  = *(const bf16x8*)&As[(wm * 64 + x * 16 + (l & 15)) * 32 + (l >> 4) * 8];
      bfr[x] = *(const bf16x8*)&Bs[(wn * 64 + x * 16 + (l & 15)) * 32 + (l >> 4) * 8];
    }
#pragma unroll
    for (int x = 0; x < 4; ++x)
#pragma unroll
      for (int y = 0; y < 4; ++y)
        acc[x][y] = __builtin_amdgcn_mfma_f32_16x16x32_bf16(af[x], bfr[y], acc[x][y], 0, 0, 0);
    __syncthreads();
  }
  const int col = l & 15, quad = l >> 4;
#pragma unroll
  for (int x = 0; x < 4; ++x) {
    const int gmB = m0 + wm * 64 + x * 16 + quad * 4;
#pragma unroll
    for (int y = 0; y < 4; ++y) {
      const int gn = n0 + wn * 64 + y * 16 + col;
      if (gn >= N) continue;
#pragma unroll
      for (int r = 0; r < 4; ++r) {
        const int gm = gmB + r;
        if (gm < M) C[(size_t)gm * N + gn] = f2bf(acc[x][y][r]);
      }
    }
  }
}

// ---------------- sequential LSTM scan, VGPR-resident weights, anti-spill ----------------
// 512 threads (8 waves -> 256 VGPR cap). Threads 0..399: 2 gate rows each (200 weight VGPRs).
// Dot loop in 5 sched_barrier-fenced groups of 5 uint4 -> <=5 live hv (caps pressure ~245).

__global__ __launch_bounds__(512, 2) void lstm_scan_reg(
    const u16* __restrict__ whh_h, const float* __restrict__ xproj,
    float* __restrict__ hseq,
    const float* __restrict__ muW, const float* __restrict__ mub,
    const float* __restrict__ lsW, const float* __restrict__ lsb,
    float* __restrict__ etas, float* __restrict__ accum, const int do_eta)
{
  __shared__ __align__(16) u32 xh2[104];
  __shared__ __align__(16) float xcat[252];
  __shared__ float ldsF[200];
  __shared__ float ldsO[200];
  __shared__ float pc[400];
  __shared__ float mu_ls[100];
  const int tid = threadIdx.x;
  const int act = (tid < 400);
  const int s = (tid >= 200) ? 1 : 0;
  const int j = tid - s * 200;
  const int rowA = s ? (200 + j) : j;
  const int rowB = s ? (600 + j) : (400 + j);
  uint4 wA[25], wB[25];
  if (act) {
    const uint4* W4 = (const uint4*)whh_h;
#pragma unroll
    for (int c = 0; c < 25; ++c) { wA[c] = W4[rowA * 25 + c]; wB[c] = W4[rowB * 25 + c]; }
  }
  if (tid < 104) xh2[tid] = 0u;
  if (tid < 252) xcat[tid] = 0.f;
  float c_reg = 0.f, klacc = 0.f;
  __syncthreads();
  for (int t = 0; t < 100; ++t) {
    float accA = 0.f, accB = 0.f;
    if (act) {
      const float xA = xproj[t * 800 + rowA];
      const float xB = xproj[t * 800 + rowB];
      float a0 = 0.f, a1 = 0.f, b0 = 0.f, b1 = 0.f;
      const uint4* H4 = (const uint4*)xh2;
#pragma unroll
      for (int g = 0; g < 5; ++g) {
#pragma unroll
        for (int c2 = 0; c2 < 5; ++c2) {
          const int c = g * 5 + c2;
          uint4 hv = H4[c];
          if (c & 1) {
            a1 = fdot2(wA[c].x, hv.x, a1); a1 = fdot2(wA[c].y, hv.y, a1);
            a1 = fdot2(wA[c].z, hv.z, a1); a1 = fdot2(wA[c].w, hv.w, a1);
            b1 = fdot2(wB[c].x, hv.x, b1); b1 = fdot2(wB[c].y, hv.y, b1);
            b1 = fdot2(wB[c].z, hv.z, b1); b1 = fdot2(wB[c].w, hv.w, b1);
          } else {
            a0 = fdot2(wA[c].x, hv.x, a0); a0 = fdot2(wA[c].y, hv.y, a0);
            a0 = fdot2(wA[c].z, hv.z, a0); a0 = fdot2(wA[c].w, hv.w, a0);
            b0 = fdot2(wB[c].x, hv.x, b0); b0 = fdot2(wB[c].y, hv.y, b0);
            b0 = fdot2(wB[c].z, hv.z, b0); b0 = fdot2(wB[c].w, hv.w, b0);
          }
        }
        __builtin_amdgcn_sched_barrier(0);   // cap live hv -> no VGPR spill
      }
      accA = a0 + a1 + xA;
      accB = b0 + b1 + xB;
      if (s) { ldsF[j] = accA; ldsO[j] = accB; }
    }
    __syncthreads();
    if (tid < 200) {
      float gi = sigm(accA);
      float gf = sigm(ldsF[j]);
      float gg = ftanh(accB);
      float go = sigm(ldsO[j]);
      c_reg = gf * c_reg + gi * gg;
      float hv = go * ftanh(c_reg);
      xcat[j] = hv;
      ((u16*)xh2)[j] = __builtin_bit_cast(u16, (f16)hv);
      if (!do_eta) hseq[t * 200 + j] = hv;
    }
    __syncthreads();
    if (do_eta) {
      if (tid < 400) {
        const int k100 = tid >> 2, s4 = tid & 3;
        const float* Wr = (k100 < 50) ? (muW + k100 * 250) : (lsW + (k100 - 50) * 250);
        const float2* Wr2 = (const float2*)Wr;
        const float2* X2 = (const float2*)xcat;
        const int p0 = s4 * 32;
        const int p1 = min(125, p0 + 32);
        float p = 0.f;
        for (int q = p0; q < p1; ++q) { float2 w2 = Wr2[q]; float2 x2 = X2[q]; p += w2.x * x2.x + w2.y * x2.y; }
        pc[tid] = p;
      }
      __syncthreads();
      if (tid < 100) {
        float v = pc[tid * 4] + pc[tid * 4 + 1] + pc[tid * 4 + 2] + pc[tid * 4 + 3];
        v += (tid < 50) ? mub[tid] : lsb[tid - 50];
        mu_ls[tid] = v;
      }
      __syncthreads();
      if (tid < 50) {
        float mu = mu_ls[tid], ls = mu_ls[50 + tid], ep = xcat[200 + tid];
        float pls = (t == 0) ? 0.f : LOG_DELTA;
        float pv = __expf(pls) + 1e-6f;
        float d = mu - ep;
        klacc += 0.5f * ((__expf(ls) + d * d) / pv - 1.f + pls - ls);
        xcat[200 + tid] = mu;
        etas[t * 50 + tid] = mu;
      }
      __syncthreads();
    }
  }
  if (do_eta) {
    if (tid < 50) ldsF[tid] = klacc;
    __syncthreads();
    if (tid == 0) { float ss = 0.f; for (int i = 0; i < 50; ++i) ss += ldsF[i]; accum[0] = ss; }
  }
}

// ---------------- theta head ----------------

__global__ __launch_bounds__(64) void k_theta(const float* __restrict__ mu_t, const float* __restrict__ ls_t,
                                              const float* __restrict__ etas, const int* __restrict__ times,
                                              float* __restrict__ theta, float* __restrict__ accum) {
  const int b = blockIdx.x, lane = threadIdx.x;
  float m_ = 0.f, l_ = 0.f, e_ = 0.f, mx = -1e30f;
  if (lane < 50) {
    m_ = mu_t[b * 50 + lane];
    l_ = ls_t[b * 50 + lane];
    e_ = etas[times[b] * 50 + lane];
    mx = m_;
  }
  for (int o = 32; o > 0; o >>= 1) mx = fmaxf(mx, __shfl_down(mx, o));
  mx = __shfl(mx, 0);
  float ex = (lane < 50) ? __expf(m_ - mx) : 0.f;
  float sum = ex;
  for (int o = 32; o > 0; o >>= 1) sum += __shfl_down(sum, o);
  sum = __shfl(sum, 0);
  if (lane < 50) theta[b * 50 + lane] = ex / sum;
  float kl = 0.f;
  if (lane < 50) {
    float d = m_ - e_;
    kl = 0.5f * ((__expf(l_) + d * d) / (1.f + 1e-6f) - 1.f - l_);
  }
  for (int o = 32; o > 0; o >>= 1) kl += __shfl_down(kl, o);
  if (lane == 0) atomicAdd(accum + 1, kl);
}

// ---------------- softmax denominators (no max-shift; |logit| small) ----------------

__global__ __launch_bounds__(256) void k_rowsum(const u16* __restrict__ logit, float* __restrict__ Z) {
  const int r = blockIdx.x, tid = threadIdx.x;
  const u32* row = (const u32*)(logit + (size_t)r * 10000);
  __shared__ float red[256];
  float s = 0.f;
  for (int v = tid; v < 5000; v += 256) {
    u32 p = row[v];
    s += __expf(bf2f((u16)(p & 0xffffu))) + __expf(bf2f((u16)(p >> 16)));
  }
  red[tid] = s; __syncthreads();
  for (int o = 128; o > 0; o >>= 1) { if (tid < o) red[tid] += red[tid + o]; __syncthreads(); }
  if (tid == 0) Z[r] = red[0];
}

// ---------------- NLL ----------------

__global__ __launch_bounds__(256) void k_nll(const u16* __restrict__ logit, const float* __restrict__ Z,
                                             const float* __restrict__ theta, const float* __restrict__ bows,
                                             const int* __restrict__ times, float* __restrict__ accum) {
  const int b = blockIdx.x, seg = blockIdx.y, tid = threadIdx.x;
  const int t = times[b];
  __shared__ float c2[52];
  __shared__ float red[256];
  if (tid < 50) c2[tid] = theta[b * 50 + tid] / Z[t * 50 + tid];
  __syncthreads();
  float part = 0.f;
  const int v0 = seg * 1250, v1 = v0 + 1250;
  const u16* base = logit + (size_t)t * 500000;
  for (int v = v0 + tid; v < v1; v += 256) {
    float ssv = 1e-12f;
#pragma unroll
    for (int k = 0; k < 50; ++k) ssv += c2[k] * __expf(bf2f(base[k * 10000 + v]));
    part += bows[b * 10000 + v] * __logf(ssv);
  }
  red[tid] = part; __syncthreads();
  for (int o = 128; o > 0; o >>= 1) { if (tid < o) red[tid] += red[tid + o]; __syncthreads(); }
  if (tid == 0) atomicAdd(accum + 3, -red[0]);
}

// ---------------- kl_alpha ----------------

__global__ __launch_bounds__(256) void k_alpha_kl(const float* __restrict__ muq, const float* __restrict__ lsq,
                                                  float* __restrict__ accum) {
  __shared__ float red[256];
  const int tid = threadIdx.x;
  float s = 0.f;
  for (int i = blockIdx.x * 256 + tid; i < 1500000; i += gridDim.x * 256) {
    int r = i % 300;
    int tk = i / 300;
    int k = tk % 50;
    int t = tk / 50;
    size_t idx = (size_t)k * 30000 + (size_t)t * 300 + r;
    float mu = muq[idx], ls = lsq[idx];
    float pm = 0.f, pls = 0.f;
    if (t > 0) { pm = muq[idx - 300]; pls = LOG_DELTA; }
    float d = mu - pm;
    s += 0.5f * ((__expf(ls) + d * d) / (__expf(pls) + 1e-6f) - 1.f + pls - ls);
  }
  red[tid] = s; __syncthreads();
  for (int o = 128; o > 0; o >>= 1) { if (tid < o) red[tid] += red[tid + o]; __syncthreads(); }
  if (tid == 0) atomicAdd(accum + 2, red[0]);
}

// ---------------- final combine ----------------

__global__ __launch_bounds__(64) void k_final(const float* __restrict__ accum, float* __restrict__ out) {
  if (threadIdx.x == 0) {
    float nll = accum[3] * COEFF;
    float kl_eta = accum[0];
    float kl_theta = accum[1] * COEFF;
    float kl_alpha = accum[2];
    out[0] = nll + kl_eta + kl_theta + kl_alpha;
    out[1] = nll;
    out[2] = kl_eta;
    out[3] = kl_theta;
    out[4] = kl_alpha;
  }
}

// ---------------- launcher ----------------

extern "C" void kernel_launch(void* const* d_in, const int* in_sizes, int n_in,
                              void* d_out, int out_size, void* d_ws, size_t ws_size,
                              hipStream_t stream) {
  (void)in_sizes; (void)n_in; (void)out_size; (void)ws_size;
  const float* bows   = (const float*)d_in[0];
  const int*   times  = (const int*)d_in[1];
  const float* rnn_in = (const float*)d_in[2];
  const float* rho_W  = (const float*)d_in[3];
  const float* muq    = (const float*)d_in[4];
  const float* lsq    = (const float*)d_in[5];
  const float* qW1    = (const float*)d_in[6];
  const float* qb1    = (const float*)d_in[7];
  const float* qW2    = (const float*)d_in[8];
  const float* qb2    = (const float*)d_in[9];
  const float* muthW  = (const float*)d_in[10];
  const float* muthb  = (const float*)d_in[11];
  const float* lsthW  = (const float*)d_in[12];
  const float* lsthb  = (const float*)d_in[13];
  const float* emW    = (const float*)d_in[14];
  const float* emb    = (const float*)d_in[15];
  const float* Wih    = (const float*)d_in[16];
  const float* Whh    = (const float*)d_in[17];
  const float* bih    = (const float*)d_in[18];
  const float* bhh    = (const float*)d_in[19];
  const float* mueW   = (const float*)d_in[20];
  const float* mueb   = (const float*)d_in[21];
  const float* lseW   = (const float*)d_in[22];
  const float* lseb   = (const float*)d_in[23];
  float* out = (float*)d_out;
  float* ws = (float*)d_ws;

  // workspace layout (float offsets); total ~117.5 MB
  float* accum = ws + 0;                       // 8
  float* nb    = ws + 8;                       // 1.28M
  float* x0    = ws + 1280008;                 // 20000
  float* xproj = ws + 1300008;                 // 80000
  float* hsA   = ws + 1380008;                 // 20000
  float* hsB   = ws + 1400008;                 // 20000
  u16*   whhh  = (u16*)(ws + 1420008);         // 480000 u16
  float* bsum  = ws + 1660008;                 // 2400
  float* etas  = ws + 1662408;                 // 5000
  float* h1    = ws + 1667408;                 // 102400
  float* h2    = ws + 1769808;                 // 102400
  float* mu_t  = ws + 1872208;                 // 6400
  float* ls_t  = ws + 1878608;                 // 6400
  float* theta = ws + 1885008;                 // 6400
  float* Zrow  = ws + 1891408;                 // 5000
  u16*   A_bf  = (u16*)(ws + 1896408);         // 5120*320 u16
  u16*   B_bf  = (u16*)(ws + 2715608);         // 10112*320 u16
  u16*   logit = (u16*)(ws + 4333528);         // 5000*10000 u16

  k_zero<<<1, 64, 0, stream>>>(accum);
  k_nb<<<128, 256, 0, stream>>>(bows, nb);
  k_cvt_f16<<<1875, 256, 0, stream>>>(Whh, whhh, 480000);
  k_bsum<<<10, 256, 0, stream>>>(bih, bhh, bsum, 2400);
  k_prep_A<<<6400, 256, 0, stream>>>(muq, A_bf);
  k_prep_B<<<12640, 256, 0, stream>>>(rho_W, B_bf);

  // x0 = rnn_inp @ eta_map_W^T + eta_map_b
  k_fill<<<79, 256, 0, stream>>>(x0, emb, 200, 20000);
  gemm_abT<0, 5><<<dim3(1, 2, 16), 256, 0, stream>>>(rnn_in, emW, nullptr, x0,
                                                     100, 200, 10000, 10000, 10000, nullptr, nullptr);

  // LSTM layers
  const float* lin[3] = {x0, hsA, hsB};
  float* lout[3] = {hsA, hsB, hsA};
  for (int l = 0; l < 3; ++l) {
    gemm_abT<0, 1><<<dim3(1, 7, 1), 256, 0, stream>>>(lin[l], Wih + l * 160000, bsum + l * 800,
                                                      xproj, 100, 800, 200, 200, 200,
                                                      nullptr, nullptr);
    lstm_scan_reg<<<1, 512, 0, stream>>>(whhh + l * 160000, xproj, lout[l],
                                         mueW, mueb, lseW, lseb, etas, accum, (l == 2) ? 1 : 0);
  }

  // theta encoder
  k_fill<<<400, 256, 0, stream>>>(h1, qb1, 800, 102400);
  gemm_abT<2, 5><<<dim3(1, 7, 24), 256, 0, stream>>>(nb, qW1, nullptr, h1,
                                                     128, 800, 10050, 10000, 10050, times, etas);
  k_relu<<<400, 256, 0, stream>>>(h1, 102400);
  gemm_abT<0, 2><<<dim3(1, 7, 1), 256, 0, stream>>>(h1, qW2, qb2, h2,
                                                    128, 800, 800, 800, 800, nullptr, nullptr);
  gemm_abT<0, 1><<<dim3(1, 1, 1), 256, 0, stream>>>(h2, muthW, muthb, mu_t,
                                                    128, 50, 800, 800, 800, nullptr, nullptr);
  gemm_abT<0, 1><<<dim3(1, 1, 1), 256, 0, stream>>>(h2, lsthW, lsthb, ls_t,
                                                    128, 50, 800, 800, 800, nullptr, nullptr);
  k_theta<<<128, 64, 0, stream>>>(mu_t, ls_t, etas, times, theta, accum);

  // beta logits (bf16 MFMA) + softmax denominators + NLL
  gemm_mfma_bT<<<dim3(40, 79), 256, 0, stream>>>(A_bf, B_bf, logit, 5000, 10000);
  k_rowsum<<<5000, 256, 0, stream>>>(logit, Zrow);
  k_nll<<<dim3(128, 8), 256, 0, stream>>>(logit, Zrow, theta, bows, times, accum);

  k_alpha_kl<<<512, 256, 0, stream>>>(muq, lsq, accum);
  k_final<<<1, 64, 0, stream>>>(accum, out);
}